// Round 10
// baseline (180.084 us; speedup 1.0000x reference)
//
#include <hip/hip_runtime.h>
#include <hip/hip_bf16.h>
#include <math.h>

// ---- static config ----
#define B_     8
#define CIN_   32
#define COUT_  32
#define H_     256
#define W_     256
#define K_     36
#define P_     3
#define KW_    7
#define TAPS_  49
#define NPAIR_ 25    // 21 within-row pairs (kx 0..5) + 4 kx=6 column pairs
#define EPS_   1e-5f
#define SLOPE_ 0.2f

// ws layout:
//   bytes [0 .. 102400)          kerB bf16 frags [4 oct][25 pair][64 lane][8]
//   bytes [102400 .. +512K)      partials float2 [256 bo][256 tile]
//   bytes [626688 .. +2K)        meanrs float2 [256 bo]
#define PART_OFF_F   25600   // float offset of partials
#define MEANRS_OFF_F 156672  // float offset of meanrs

// Xup: ONE ci-octet per pass, parity-split, 38 rows (row 37 = zero pad
// read by the (ky6,pad) half of the last column pair):
//   even-x: 38 rows x 19 entries  base 0      11552 B
//   odd-x:  38 rows x 19 entries  base 11552  11552 B
// entry = 16 B (8 bf16 ci octet). row stride 304 B (=19*16 -> stage-2
// stores stay perfectly linear across y boundaries). total 23104 B.
#define XP_ROW   304
#define XO_BASE  11552

using short8_t  = __attribute__((ext_vector_type(8)))  short;
using f32x16_t  = __attribute__((ext_vector_type(16))) float;
using f32x4_t   = __attribute__((ext_vector_type(4)))  float;

__device__ inline ushort f32_to_bf16(float f) {
    unsigned int bits = __float_as_uint(f);
    unsigned int r = (bits + 0x7FFFu + ((bits >> 16) & 1u)) >> 16;
    return (ushort)r;
}

// pair pi, half tt -> linear tap (0..48), or -1 if zero pad
__host__ __device__ inline int pair_tap(int pi, int tt) {
    if (pi < 21) {
        const int ky = pi / 3, c = pi % 3;
        return ky * 7 + 2 * c + tt;
    }
    const int row = 2 * (pi - 21) + tt;
    return (row <= 6) ? (row * 7 + 6) : -1;
}

// ============================================================
// Kernel A: build B-fragments in the 25-pair packing. (r16, validated)
// ============================================================
__global__ __launch_bounds__(256)
void build_kernel(const float* __restrict__ weight, ushort* __restrict__ kerB) {
    __shared__ float psi_s[2][K_];            // psi for the pair's two taps
    const int f  = blockIdx.x;
    const int pi = f % NPAIR_;
    const int oc = f / NPAIR_;
    const int tid = threadIdx.x;

    if (tid < 2 * K_) {
        const int tt = tid / K_;              // which tap of the pair
        const int k  = tid - tt * K_;
        const int tap = pair_tap(pi, tt);
        float val = 0.f;
        if (tap >= 0) {
            const int ky = tap / 7;
            const int kx = tap % 7;
            const double dxy   = 2.0 / 512.0;
            const double rcut  = 0.015;       // RADIUS_CUTOFF / 2
            const int    nr    = 6, nphi = 7;
            const double dr    = rcut / nr;
            const double dphi  = 2.0 * M_PI / nphi;
            const double norm  = M_PI * (rcut * nr / (nr + 1)) * (rcut * nr / (nr + 1));
            const double q     = dxy * dxy;
            const double offy = (double)(ky - P_) * dxy;
            const double offx = (double)(kx - P_) * dxy;
            const double r    = sqrt(offx * offx + offy * offy);
            double phi = atan2(offy, offx);
            if (phi < 0.0) phi += 2.0 * M_PI;
            double ir, iphi;
            if (k == 0) { ir = 0.0; iphi = 0.0; }
            else        { ir = (double)((k - 1) / nphi + 1) * dr;
                          iphi = (double)((k - 1) % nphi) * dphi; }
            double rv = 1.0 - fabs(r - ir) / dr;
            rv = rv > 0.0 ? rv : 0.0;
            if (r > rcut) rv = 0.0;
            double pv = 1.0;
            if (k > 0) {
                double da = fabs(phi - iphi);
                double dm = da < (2.0 * M_PI - da) ? da : (2.0 * M_PI - da);
                pv = 1.0 - dm / dphi;
                pv = pv > 0.0 ? pv : 0.0;
            }
            val = (float)(rv * pv * q / norm);
        }
        psi_s[tt][k] = val;
    }
    __syncthreads();

    for (int e = tid; e < 512; e += 256) {
        const int lane = e >> 3;
        const int j    = e & 7;
        const int gs   = lane >> 5;
        const int n    = lane & 31;
        float s = 0.f;
        if (pair_tap(pi, gs) >= 0) {
            const int ci = oc * 8 + j;
            const float* w = weight + (size_t)(n * CIN_ + ci) * K_;
            #pragma unroll
            for (int k = 0; k < K_; ++k) s = fmaf(w[k], psi_s[gs][k], s);
        }
        kerB[((size_t)f * 64 + lane) * 8 + j] = f32_to_bf16(s);
    }
}

// ============================================================
// Kernel B: fused upsample + implicit-GEMM conv + stats partials.
// grid = (16,16,B), block = 512 (8 waves). Tile = 16x16 pixels x 32 cout.
// r18 = r16 stage-3/epilogue + stage-2-FROM-GLOBAL:
//   Img_s staging deleted. Per half-item (4 ci), 16 clamped scalar
//   global loads (L1/L2-served; lanes sweep consecutive cols ->
//   coalesced), lerp in registers, 2x b64 stores into the SAME Xup
//   layout. Clamp replaces zero-fill: at clamped edges the lerp weight
//   is exactly 0/1, differences <= 1 f32 ulp. Removes ~430 wave-LDS
//   ops/block and 4 of 12 barriers.
// ============================================================
__global__ __launch_bounds__(512, 8)
void conv_mfma(const float* __restrict__ image,
               const ushort* __restrict__ kerB,
               float* __restrict__ out,
               float* __restrict__ partials) {
    __shared__ ushort Xup_s[11552];           // 23104 B (parity-split, 38 rows)
    __shared__ float  wp[8][32][2];           // per-wave stats partials

    const int tid  = threadIdx.x;
    const int lane = tid & 63;
    const int w    = tid >> 6;                // wave 0..7 = M-tile index
    const int j0 = blockIdx.x * 16;
    const int i0 = blockIdx.y * 16;
    const int b  = blockIdx.z;

    const int u0 = 2 * i0 - 3;
    const int v0 = 2 * j0 - 3;
    const int R0 = i0 - 2;                    // unclamped patch origin (rows)
    const int C0 = j0 - 2;                    // unclamped patch origin (cols)

    // A-fragment lane mapping (32x32x16): m = lane&31, k-half gs = lane>>5
    const int gs  = lane >> 5;                // which tap of the pair
    const int tio = (lane & 31) >> 4;
    const int tj  = lane & 15;
    const int yb0 = 4 * w + 2 * tio;

    f32x16_t acc;
    #pragma unroll
    for (int q = 0; q < 16; ++q) acc[q] = 0.f;

    char* xup_bytes = (char*)Xup_s;

    // zero Xup even row 37 (pad) once; never overwritten afterwards
    if (tid < 19) {
        const short8_t z = {0,0,0,0,0,0,0,0};
        *(short8_t*)(xup_bytes + 37 * XP_ROW + tid * 16) = z;
    }
    __syncthreads();

    const float* imgb = image + (size_t)(b * CIN_) * (H_ * W_);

    for (int oc = 0; oc < 4; ++oc) {
        // ---- stage 2: polyphase upsample straight from global ----
        // half-item e -> (item = e>>1, p = e&1); item -> (y 0..36, xp 0..18).
        // ry = y>>1; wy = ((y&1)?510:255 - (R0+ry))/511 (align_corners 2x).
        // Loads use CLAMPED indices; outputs masked by ok flags.
        for (int e = tid; e < 1406; e += 512) {
            const int item = e >> 1;
            const int p    = e & 1;           // ci quad within octet
            const int y    = item / 19;
            const int xp   = item - 19 * y;
            const int ry   = y >> 1;
            const int r0   = R0 + ry;
            const int c0   = C0 + xp;
            const float wy  = (float)(((y & 1) ? 510 : 255) - r0) * (1.0f / 511.0f);
            const float wx0 = (float)(255 - c0) * (1.0f / 511.0f);
            const float wx1 = (float)(510 - c0) * (1.0f / 511.0f);
            const bool oky = ((unsigned)(u0 + y) < 512u);
            const bool ok0 = oky && ((unsigned)(v0 + 2 * xp) < 512u);
            const bool ok1 = oky && ((unsigned)(v0 + 2 * xp + 1) < 512u) && (xp < 18);

            const int r0c = r0 < 0 ? 0 : (r0 > 255 ? 255 : r0);
            const int r1t = r0 + 1;
            const int r1c = r1t < 0 ? 0 : (r1t > 255 ? 255 : r1t);
            const int c0c = c0 < 0 ? 0 : (c0 > 255 ? 255 : c0);
            const int c1t = c0 + 1;
            const int c1c = c1t < 0 ? 0 : (c1t > 255 ? 255 : c1t);

            const float* pl = imgb + (size_t)(oc * 8 + p * 4) * (H_ * W_);
            const int o00 = r0c * W_ + c0c, o01 = r0c * W_ + c1c;
            const int o10 = r1c * W_ + c0c, o11 = r1c * W_ + c1c;

            float ve[4], vo[4];
            #pragma unroll
            for (int c = 0; c < 4; ++c) {
                const float* q = pl + (size_t)c * (H_ * W_);
                const float v00 = q[o00];
                const float v01 = q[o01];
                const float v10 = q[o10];
                const float v11 = q[o11];
                const float l0 = v00 + wy * (v10 - v00);
                const float l1 = v01 + wy * (v11 - v01);
                ve[c] = l0 + wx0 * (l1 - l0);
                vo[c] = l0 + wx1 * (l1 - l0);
            }
            __hip_bfloat162 he0 = __float22bfloat162_rn(make_float2(ve[0], ve[1]));
            __hip_bfloat162 he1 = __float22bfloat162_rn(make_float2(ve[2], ve[3]));
            __hip_bfloat162 ho0 = __float22bfloat162_rn(make_float2(vo[0], vo[1]));
            __hip_bfloat162 ho1 = __float22bfloat162_rn(make_float2(vo[2], vo[3]));
            uint2 pe, po;
            pe.x = ok0 ? *(unsigned int*)&he0 : 0u;
            pe.y = ok0 ? *(unsigned int*)&he1 : 0u;
            po.x = ok1 ? *(unsigned int*)&ho0 : 0u;
            po.y = ok1 ? *(unsigned int*)&ho1 : 0u;
            const int sbase = y * XP_ROW + xp * 16 + p * 8;
            *(uint2*)(xup_bytes + sbase) = pe;
            *(uint2*)(xup_bytes + XO_BASE + sbase) = po;
        }
        __syncthreads();

        // ---- stage 3: 21 within-row pairs + 4 column pairs = 25 MFMAs ----
        const ushort* kbp = kerB + ((size_t)(oc * NPAIR_) * 64 + lane) * 8;
        // group A base: parity buffer = gs, row yb0+ky, entry tj+c
        const int baseA = (gs ? XO_BASE : 0) + yb0 * XP_ROW + tj * 16;
        // group B base: even buffer, row yb0+2q+gs, entry tj+3
        const int baseB = (yb0 + gs) * XP_ROW + (tj + 3) * 16;

        #pragma unroll
        for (int ky = 0; ky < KW_; ++ky) {
            short8_t bf0 = *(const short8_t*)(kbp + (size_t)((ky * 3 + 0) * 512));
            short8_t bf1 = *(const short8_t*)(kbp + (size_t)((ky * 3 + 1) * 512));
            short8_t bf2 = *(const short8_t*)(kbp + (size_t)((ky * 3 + 2) * 512));
            const int rbase = baseA + ky * XP_ROW;
            const short8_t a0 = *(const short8_t*)(xup_bytes + rbase);
            acc = __builtin_amdgcn_mfma_f32_32x32x16_bf16(a0, bf0, acc, 0, 0, 0);
            const short8_t a1 = *(const short8_t*)(xup_bytes + rbase + 16);
            acc = __builtin_amdgcn_mfma_f32_32x32x16_bf16(a1, bf1, acc, 0, 0, 0);
            const short8_t a2 = *(const short8_t*)(xup_bytes + rbase + 32);
            acc = __builtin_amdgcn_mfma_f32_32x32x16_bf16(a2, bf2, acc, 0, 0, 0);
        }
        #pragma unroll
        for (int q = 0; q < 4; ++q) {
            const short8_t bfq =
                *(const short8_t*)(kbp + (size_t)((21 + q) * 512));
            const short8_t aq =
                *(const short8_t*)(xup_bytes + baseB + q * (2 * XP_ROW));
            acc = __builtin_amdgcn_mfma_f32_32x32x16_bf16(aq, bfq, acc, 0, 0, 0);
        }
        __syncthreads();   // before next pass's staging overwrites LDS
    }

    // ---- epilogue: C-writes (layout col n=lane&31, row m=(q&3)+8*(q>>2)+4*gs)
    const int n = lane & 31;
    float* op = out + (size_t)(b * COUT_ + n) * (H_ * W_);
    const int ibase = i0 + 2 * w;
    #pragma unroll
    for (int grp = 0; grp < 4; ++grp) {
        const int ti  = ibase + (grp >> 1);
        const int tjj = j0 + ((grp & 1) ? 8 : 0) + 4 * gs;
        f32x4_t s;
        s[0] = acc[grp * 4 + 0]; s[1] = acc[grp * 4 + 1];
        s[2] = acc[grp * 4 + 2]; s[3] = acc[grp * 4 + 3];
        *(f32x4_t*)(op + (size_t)ti * W_ + tjj) = s;
    }

    // ---- epilogue: InstanceNorm partial sums from registers ----
    float s1 = 0.f, s2 = 0.f;
    #pragma unroll
    for (int q = 0; q < 16; ++q) { s1 += acc[q]; s2 = fmaf(acc[q], acc[q], s2); }
    s1 += __shfl_xor(s1, 32);
    s2 += __shfl_xor(s2, 32);
    if (lane < 32) { wp[w][lane][0] = s1; wp[w][lane][1] = s2; }
    __syncthreads();
    if (tid < 32) {
        float t1 = 0.f, t2 = 0.f;
        #pragma unroll
        for (int wv = 0; wv < 8; ++wv) { t1 += wp[wv][tid][0]; t2 += wp[wv][tid][1]; }
        const int tile = blockIdx.y * 16 + blockIdx.x;
        float2* pp = (float2*)partials;
        pp[((b * 32 + tid) << 8) | tile] = make_float2(t1, t2);
    }
}

// ============================================================
// Kernel C1: per-channel stats finalize. grid = 256 (one wave each).
// Fixed-order shfl tree -> deterministic.
// ============================================================
__global__ __launch_bounds__(64)
void stats_kernel(const float* __restrict__ partials, float* __restrict__ meanrs) {
    const int bo = blockIdx.x;                 // channel (b*32+o)
    const int l  = threadIdx.x;                // 0..63
    const float2* pp = (const float2*)partials + ((size_t)bo << 8);
    float s1 = 0.f, s2 = 0.f;
    #pragma unroll
    for (int k = 0; k < 4; ++k) {
        const float2 p = pp[l + 64 * k];
        s1 += p.x; s2 += p.y;
    }
    #pragma unroll
    for (int off = 32; off > 0; off >>= 1) {
        s1 += __shfl_down(s1, off);
        s2 += __shfl_down(s2, off);
    }
    if (l == 0) {
        const float inv = 1.0f / 65536.0f;
        const float m   = s1 * inv;
        const float var = s2 * inv - m * m;
        ((float2*)meanrs)[bo] = make_float2(m, 1.0f / sqrtf(var + EPS_));
    }
}

// ============================================================
// Kernel C2: pure-stream normalize + LeakyReLU (no LDS, no barriers).
// grid = 16384, block = 256.
// ============================================================
__global__ __launch_bounds__(256)
void norm2_kernel(float* __restrict__ y, const float* __restrict__ meanrs) {
    const int blk = blockIdx.x;
    const int bo  = blk >> 6;                  // 64 blocks per channel
    const float2 mr = ((const float2*)meanrs)[bo];
    const float m  = mr.x;
    const float rs = mr.y;

    const int e = blk * 256 + threadIdx.x;     // float4 index
    float4 v = ((const float4*)y)[e];
    v.x = (v.x - m) * rs; v.x = v.x >= 0.f ? v.x : SLOPE_ * v.x;
    v.y = (v.y - m) * rs; v.y = v.y >= 0.f ? v.y : SLOPE_ * v.y;
    v.z = (v.z - m) * rs; v.z = v.z >= 0.f ? v.z : SLOPE_ * v.z;
    v.w = (v.w - m) * rs; v.w = v.w >= 0.f ? v.w : SLOPE_ * v.w;
    ((float4*)y)[e] = v;
}

// ============================================================
extern "C" void kernel_launch(void* const* d_in, const int* in_sizes, int n_in,
                              void* d_out, int out_size, void* d_ws, size_t ws_size,
                              hipStream_t stream) {
    const float* image  = (const float*)d_in[0];
    const float* weight = (const float*)d_in[1];
    float*  out      = (float*)d_out;
    ushort* kerB     = (ushort*)d_ws;
    float*  partials = (float*)d_ws + PART_OFF_F;
    float*  meanrs   = (float*)d_ws + MEANRS_OFF_F;

    build_kernel<<<dim3(4 * NPAIR_), dim3(256), 0, stream>>>(weight, kerB);
    conv_mfma<<<dim3(16, 16, B_), dim3(512), 0, stream>>>(image, kerB, out, partials);
    stats_kernel<<<dim3(256), dim3(64), 0, stream>>>(partials, meanrs);
    norm2_kernel<<<dim3(16384), dim3(256), 0, stream>>>(out, meanrs);
}

// Round 11
// 125.627 us; speedup vs baseline: 1.4335x; 1.4335x over previous
//
#include <hip/hip_runtime.h>
#include <hip/hip_bf16.h>
#include <math.h>

// ---- static config ----
#define B_     8
#define CIN_   32
#define COUT_  32
#define H_     256
#define W_     256
#define K_     36
#define P_     3
#define KW_    7
#define TAPS_  49
#define NPAIR_ 25    // 21 within-row pairs (kx 0..5) + 4 kx=6 column pairs
#define EPS_   1e-5f
#define SLOPE_ 0.2f

// ws layout:
//   bytes [0 .. 102400)          kerB bf16 frags [4 oct][25 pair][64 lane][8]
//   bytes [102400 .. +512K)      partials float2 [256 bo][256 tile]
//   bytes [626688 .. +2K)        meanrs float2 [256 bo]
#define PART_OFF_F   25600   // float offset of partials
#define MEANRS_OFF_F 156672  // float offset of meanrs

// Img_s: fp32, 2 planes [ci-quad][20 py][21 px][4 ci], plane 6736 B
#define IMG_PLANE_B   6736
#define IMG_ROW_B     336

// Xup: ONE ci-octet per pass, parity-split, 38 rows (row 37 = zero pad
// read by the (ky6,pad) half of the last column pair; quad stage-2
// re-writes it with mask-forced zeros every pass):
//   even-x: 38 rows x 19 entries  base 0      11552 B
//   odd-x:  38 rows x 19 entries  base 11552  11552 B
// entry = 16 B (8 bf16 ci octet). row stride 304 B. total 23104 B.
#define XP_ROW   304
#define XO_BASE  11552

using short8_t  = __attribute__((ext_vector_type(8)))  short;
using f32x16_t  = __attribute__((ext_vector_type(16))) float;
using f32x4_t   = __attribute__((ext_vector_type(4)))  float;

__device__ inline ushort f32_to_bf16(float f) {
    unsigned int bits = __float_as_uint(f);
    unsigned int r = (bits + 0x7FFFu + ((bits >> 16) & 1u)) >> 16;
    return (ushort)r;
}

// pair pi, half tt -> linear tap (0..48), or -1 if zero pad
__host__ __device__ inline int pair_tap(int pi, int tt) {
    if (pi < 21) {
        const int ky = pi / 3, c = pi % 3;
        return ky * 7 + 2 * c + tt;
    }
    const int row = 2 * (pi - 21) + tt;
    return (row <= 6) ? (row * 7 + 6) : -1;
}

// ============================================================
// Kernel A: build B-fragments in the 25-pair packing. (r16, validated)
// ============================================================
__global__ __launch_bounds__(256)
void build_kernel(const float* __restrict__ weight, ushort* __restrict__ kerB) {
    __shared__ float psi_s[2][K_];            // psi for the pair's two taps
    const int f  = blockIdx.x;
    const int pi = f % NPAIR_;
    const int oc = f / NPAIR_;
    const int tid = threadIdx.x;

    if (tid < 2 * K_) {
        const int tt = tid / K_;              // which tap of the pair
        const int k  = tid - tt * K_;
        const int tap = pair_tap(pi, tt);
        float val = 0.f;
        if (tap >= 0) {
            const int ky = tap / 7;
            const int kx = tap % 7;
            const double dxy   = 2.0 / 512.0;
            const double rcut  = 0.015;       // RADIUS_CUTOFF / 2
            const int    nr    = 6, nphi = 7;
            const double dr    = rcut / nr;
            const double dphi  = 2.0 * M_PI / nphi;
            const double norm  = M_PI * (rcut * nr / (nr + 1)) * (rcut * nr / (nr + 1));
            const double q     = dxy * dxy;
            const double offy = (double)(ky - P_) * dxy;
            const double offx = (double)(kx - P_) * dxy;
            const double r    = sqrt(offx * offx + offy * offy);
            double phi = atan2(offy, offx);
            if (phi < 0.0) phi += 2.0 * M_PI;
            double ir, iphi;
            if (k == 0) { ir = 0.0; iphi = 0.0; }
            else        { ir = (double)((k - 1) / nphi + 1) * dr;
                          iphi = (double)((k - 1) % nphi) * dphi; }
            double rv = 1.0 - fabs(r - ir) / dr;
            rv = rv > 0.0 ? rv : 0.0;
            if (r > rcut) rv = 0.0;
            double pv = 1.0;
            if (k > 0) {
                double da = fabs(phi - iphi);
                double dm = da < (2.0 * M_PI - da) ? da : (2.0 * M_PI - da);
                pv = 1.0 - dm / dphi;
                pv = pv > 0.0 ? pv : 0.0;
            }
            val = (float)(rv * pv * q / norm);
        }
        psi_s[tt][k] = val;
    }
    __syncthreads();

    for (int e = tid; e < 512; e += 256) {
        const int lane = e >> 3;
        const int j    = e & 7;
        const int gs   = lane >> 5;
        const int n    = lane & 31;
        float s = 0.f;
        if (pair_tap(pi, gs) >= 0) {
            const int ci = oc * 8 + j;
            const float* w = weight + (size_t)(n * CIN_ + ci) * K_;
            #pragma unroll
            for (int k = 0; k < K_; ++k) s = fmaf(w[k], psi_s[gs][k], s);
        }
        kerB[((size_t)f * 64 + lane) * 8 + j] = f32_to_bf16(s);
    }
}

// ============================================================
// Kernel B: fused upsample + implicit-GEMM conv + stats partials.
// grid = (16,16,B), block = 512 (8 waves). Tile = 16x16 pixels x 32 cout.
// r19 = r16 body (validated 102.5 us conv) with stage-2 as QUAD items:
//   item (ry,xp) -> 4 outputs (2y x 2x) sharing the same 8 Img corners.
//   Plane-SEQUENTIAL (#pragma unroll 1) with recompute: live set =
//   4 corners + 4 y-lerp cols + 1 out temp, all named scalars -> no
//   spill (r13's trap). Stage-2 LDS reads: 2/output (was 4).
//   Also: post-stage-3 barrier skipped on the last pass.
// ============================================================
__global__ __launch_bounds__(512, 8)
void conv_mfma(const float* __restrict__ image,
               const ushort* __restrict__ kerB,
               float* __restrict__ out,
               float* __restrict__ partials) {
    __shared__ float  Img_s[3368];            // 13472 B (2 planes x 6736 B)
    __shared__ ushort Xup_s[11552];           // 23104 B (parity-split, 38 rows)
    __shared__ float  wp[8][32][2];           // per-wave stats partials

    const int tid  = threadIdx.x;
    const int lane = tid & 63;
    const int w    = tid >> 6;                // wave 0..7 = M-tile index
    const int j0 = blockIdx.x * 16;
    const int i0 = blockIdx.y * 16;
    const int b  = blockIdx.z;

    const int u0 = 2 * i0 - 3;
    const int v0 = 2 * j0 - 3;
    const int R0 = i0 - 2;                    // unclamped patch origin (rows)
    const int C0 = j0 - 2;                    // unclamped patch origin (cols)

    // A-fragment lane mapping (32x32x16): m = lane&31, k-half gs = lane>>5
    const int gs  = lane >> 5;                // which tap of the pair
    const int tio = (lane & 31) >> 4;
    const int tj  = lane & 15;
    const int yb0 = 4 * w + 2 * tio;

    f32x16_t acc;
    #pragma unroll
    for (int q = 0; q < 16; ++q) acc[q] = 0.f;

    char* img_bytes = (char*)Img_s;
    char* xup_bytes = (char*)Xup_s;

    // zero Xup even row 37 (pad) before first pass; stage-2 re-writes it
    // with mask-forced zeros every pass thereafter.
    if (tid < 19) {
        const short8_t z = {0,0,0,0,0,0,0,0};
        *(short8_t*)(xup_bytes + 37 * XP_ROW + tid * 16) = z;
    }

    const float* imgb = image + (size_t)(b * CIN_) * (H_ * W_);

    for (int oc = 0; oc < 4; ++oc) {
        // ---- stage 1: 20x20 patch, 2 ci-quad planes of this octet ----
        const float* img = imgb + (size_t)(oc * 8) * (H_ * W_);
        for (int e = tid; e < 800; e += 512) {
            const int p  = (e >= 400) ? 1 : 0;       // ci quad within octet
            const int yx = e - p * 400;
            const int py = yx / 20, px = yx - py * 20;
            const int row = R0 + py, col = C0 + px;
            f32x4_t g = {0.f, 0.f, 0.f, 0.f};
            if ((unsigned)row < 256u && (unsigned)col < 256u) {
                const float* q = img + (size_t)p * 4 * (H_ * W_) + row * W_ + col;
                g[0] = q[0];
                g[1] = q[H_ * W_];
                g[2] = q[2 * (H_ * W_)];
                g[3] = q[3 * (H_ * W_)];
            }
            *(f32x4_t*)(img_bytes + p * IMG_PLANE_B + (py * 21 + px) * 16) = g;
        }
        __syncthreads();

        // ---- stage 2: quad items (y-pair x x-pair), plane-sequential ----
        // align_corners 2x exact: wy_even = (255-(R0+ry))/511,
        // wy_odd = (510-(R0+ry))/511; same in x. All 4 outputs of a quad
        // share the 8 corners of (ry..ry+1, xp..xp+1).
        for (int e = tid; e < 361; e += 512) {
            const int ry = e / 19;
            const int xp = e - 19 * ry;
            const int r0 = R0 + ry;
            const int c0 = C0 + xp;
            const float wye = (float)(255 - r0) * (1.0f / 511.0f);
            const float wyo = (float)(510 - r0) * (1.0f / 511.0f);
            const float wx0 = (float)(255 - c0) * (1.0f / 511.0f);
            const float wx1 = (float)(510 - c0) * (1.0f / 511.0f);
            const int ye = 2 * ry, yo = 2 * ry + 1;
            const bool okye = ((unsigned)(u0 + ye) < 512u);
            const bool okyo = ((unsigned)(u0 + yo) < 512u) && (ry < 18);
            const bool okx0 = ((unsigned)(v0 + 2 * xp) < 512u);
            const bool okx1 = ((unsigned)(v0 + 2 * xp + 1) < 512u) && (xp < 18);
            const int sbE = ye * XP_ROW + xp * 16;   // even-y row base
            const int sbO = yo * XP_ROW + xp * 16;   // odd-y row base (37=pad, masked 0)

            #pragma unroll 1
            for (int p = 0; p < 2; ++p) {
                const char* lo = img_bytes + p * IMG_PLANE_B + (ry * 21 + xp) * 16;
                const f32x4_t a00 = *(const f32x4_t*)(lo);
                const f32x4_t a10 = *(const f32x4_t*)(lo + IMG_ROW_B);
                const f32x4_t ce0 = a00 + wye * (a10 - a00);
                const f32x4_t co0 = a00 + wyo * (a10 - a00);
                const f32x4_t a01 = *(const f32x4_t*)(lo + 16);
                const f32x4_t a11 = *(const f32x4_t*)(lo + IMG_ROW_B + 16);
                const f32x4_t ce1 = a01 + wye * (a11 - a01);
                const f32x4_t co1 = a01 + wyo * (a11 - a01);
                const int po = p * 8;

                {   // (y even, x even) -> even buffer
                    const f32x4_t v = ce0 + wx0 * (ce1 - ce0);
                    __hip_bfloat162 h0 = __float22bfloat162_rn(make_float2(v[0], v[1]));
                    __hip_bfloat162 h1 = __float22bfloat162_rn(make_float2(v[2], v[3]));
                    uint2 pk;
                    pk.x = (okye && okx0) ? *(unsigned int*)&h0 : 0u;
                    pk.y = (okye && okx0) ? *(unsigned int*)&h1 : 0u;
                    *(uint2*)(xup_bytes + sbE + po) = pk;
                }
                {   // (y even, x odd) -> odd buffer
                    const f32x4_t v = ce0 + wx1 * (ce1 - ce0);
                    __hip_bfloat162 h0 = __float22bfloat162_rn(make_float2(v[0], v[1]));
                    __hip_bfloat162 h1 = __float22bfloat162_rn(make_float2(v[2], v[3]));
                    uint2 pk;
                    pk.x = (okye && okx1) ? *(unsigned int*)&h0 : 0u;
                    pk.y = (okye && okx1) ? *(unsigned int*)&h1 : 0u;
                    *(uint2*)(xup_bytes + XO_BASE + sbE + po) = pk;
                }
                {   // (y odd, x even) -> even buffer (row 37 = masked 0 pad)
                    const f32x4_t v = co0 + wx0 * (co1 - co0);
                    __hip_bfloat162 h0 = __float22bfloat162_rn(make_float2(v[0], v[1]));
                    __hip_bfloat162 h1 = __float22bfloat162_rn(make_float2(v[2], v[3]));
                    uint2 pk;
                    pk.x = (okyo && okx0) ? *(unsigned int*)&h0 : 0u;
                    pk.y = (okyo && okx0) ? *(unsigned int*)&h1 : 0u;
                    *(uint2*)(xup_bytes + sbO + po) = pk;
                }
                {   // (y odd, x odd) -> odd buffer
                    const f32x4_t v = co0 + wx1 * (co1 - co0);
                    __hip_bfloat162 h0 = __float22bfloat162_rn(make_float2(v[0], v[1]));
                    __hip_bfloat162 h1 = __float22bfloat162_rn(make_float2(v[2], v[3]));
                    uint2 pk;
                    pk.x = (okyo && okx1) ? *(unsigned int*)&h0 : 0u;
                    pk.y = (okyo && okx1) ? *(unsigned int*)&h1 : 0u;
                    *(uint2*)(xup_bytes + XO_BASE + sbO + po) = pk;
                }
            }
        }
        __syncthreads();

        // ---- stage 3: 21 within-row pairs + 4 column pairs = 25 MFMAs ----
        const ushort* kbp = kerB + ((size_t)(oc * NPAIR_) * 64 + lane) * 8;
        // group A base: parity buffer = gs, row yb0+ky, entry tj+c
        const int baseA = (gs ? XO_BASE : 0) + yb0 * XP_ROW + tj * 16;
        // group B base: even buffer, row yb0+2q+gs, entry tj+3
        const int baseB = (yb0 + gs) * XP_ROW + (tj + 3) * 16;

        #pragma unroll
        for (int ky = 0; ky < KW_; ++ky) {
            short8_t bf0 = *(const short8_t*)(kbp + (size_t)((ky * 3 + 0) * 512));
            short8_t bf1 = *(const short8_t*)(kbp + (size_t)((ky * 3 + 1) * 512));
            short8_t bf2 = *(const short8_t*)(kbp + (size_t)((ky * 3 + 2) * 512));
            const int rbase = baseA + ky * XP_ROW;
            const short8_t a0 = *(const short8_t*)(xup_bytes + rbase);
            acc = __builtin_amdgcn_mfma_f32_32x32x16_bf16(a0, bf0, acc, 0, 0, 0);
            const short8_t a1 = *(const short8_t*)(xup_bytes + rbase + 16);
            acc = __builtin_amdgcn_mfma_f32_32x32x16_bf16(a1, bf1, acc, 0, 0, 0);
            const short8_t a2 = *(const short8_t*)(xup_bytes + rbase + 32);
            acc = __builtin_amdgcn_mfma_f32_32x32x16_bf16(a2, bf2, acc, 0, 0, 0);
        }
        #pragma unroll
        for (int q = 0; q < 4; ++q) {
            const short8_t bfq =
                *(const short8_t*)(kbp + (size_t)((21 + q) * 512));
            const short8_t aq =
                *(const short8_t*)(xup_bytes + baseB + q * (2 * XP_ROW));
            acc = __builtin_amdgcn_mfma_f32_32x32x16_bf16(aq, bfq, acc, 0, 0, 0);
        }
        if (oc != 3) __syncthreads();   // last pass: epilogue touches only wp
    }

    // ---- epilogue: C-writes (layout col n=lane&31, row m=(q&3)+8*(q>>2)+4*gs)
    const int n = lane & 31;
    float* op = out + (size_t)(b * COUT_ + n) * (H_ * W_);
    const int ibase = i0 + 2 * w;
    #pragma unroll
    for (int grp = 0; grp < 4; ++grp) {
        const int ti  = ibase + (grp >> 1);
        const int tjj = j0 + ((grp & 1) ? 8 : 0) + 4 * gs;
        f32x4_t s;
        s[0] = acc[grp * 4 + 0]; s[1] = acc[grp * 4 + 1];
        s[2] = acc[grp * 4 + 2]; s[3] = acc[grp * 4 + 3];
        *(f32x4_t*)(op + (size_t)ti * W_ + tjj) = s;
    }

    // ---- epilogue: InstanceNorm partial sums from registers ----
    float s1 = 0.f, s2 = 0.f;
    #pragma unroll
    for (int q = 0; q < 16; ++q) { s1 += acc[q]; s2 = fmaf(acc[q], acc[q], s2); }
    s1 += __shfl_xor(s1, 32);
    s2 += __shfl_xor(s2, 32);
    if (lane < 32) { wp[w][lane][0] = s1; wp[w][lane][1] = s2; }
    __syncthreads();
    if (tid < 32) {
        float t1 = 0.f, t2 = 0.f;
        #pragma unroll
        for (int wv = 0; wv < 8; ++wv) { t1 += wp[wv][tid][0]; t2 += wp[wv][tid][1]; }
        const int tile = blockIdx.y * 16 + blockIdx.x;
        float2* pp = (float2*)partials;
        pp[((b * 32 + tid) << 8) | tile] = make_float2(t1, t2);
    }
}

// ============================================================
// Kernel C1: per-channel stats finalize. grid = 256 (one wave each).
// Fixed-order shfl tree -> deterministic.
// ============================================================
__global__ __launch_bounds__(64)
void stats_kernel(const float* __restrict__ partials, float* __restrict__ meanrs) {
    const int bo = blockIdx.x;                 // channel (b*32+o)
    const int l  = threadIdx.x;                // 0..63
    const float2* pp = (const float2*)partials + ((size_t)bo << 8);
    float s1 = 0.f, s2 = 0.f;
    #pragma unroll
    for (int k = 0; k < 4; ++k) {
        const float2 p = pp[l + 64 * k];
        s1 += p.x; s2 += p.y;
    }
    #pragma unroll
    for (int off = 32; off > 0; off >>= 1) {
        s1 += __shfl_down(s1, off);
        s2 += __shfl_down(s2, off);
    }
    if (l == 0) {
        const float inv = 1.0f / 65536.0f;
        const float m   = s1 * inv;
        const float var = s2 * inv - m * m;
        ((float2*)meanrs)[bo] = make_float2(m, 1.0f / sqrtf(var + EPS_));
    }
}

// ============================================================
// Kernel C2: pure-stream normalize + LeakyReLU (no LDS, no barriers).
// grid = 16384, block = 256.
// ============================================================
__global__ __launch_bounds__(256)
void norm2_kernel(float* __restrict__ y, const float* __restrict__ meanrs) {
    const int blk = blockIdx.x;
    const int bo  = blk >> 6;                  // 64 blocks per channel
    const float2 mr = ((const float2*)meanrs)[bo];
    const float m  = mr.x;
    const float rs = mr.y;

    const int e = blk * 256 + threadIdx.x;     // float4 index
    float4 v = ((const float4*)y)[e];
    v.x = (v.x - m) * rs; v.x = v.x >= 0.f ? v.x : SLOPE_ * v.x;
    v.y = (v.y - m) * rs; v.y = v.y >= 0.f ? v.y : SLOPE_ * v.y;
    v.z = (v.z - m) * rs; v.z = v.z >= 0.f ? v.z : SLOPE_ * v.z;
    v.w = (v.w - m) * rs; v.w = v.w >= 0.f ? v.w : SLOPE_ * v.w;
    ((float4*)y)[e] = v;
}

// ============================================================
extern "C" void kernel_launch(void* const* d_in, const int* in_sizes, int n_in,
                              void* d_out, int out_size, void* d_ws, size_t ws_size,
                              hipStream_t stream) {
    const float* image  = (const float*)d_in[0];
    const float* weight = (const float*)d_in[1];
    float*  out      = (float*)d_out;
    ushort* kerB     = (ushort*)d_ws;
    float*  partials = (float*)d_ws + PART_OFF_F;
    float*  meanrs   = (float*)d_ws + MEANRS_OFF_F;

    build_kernel<<<dim3(4 * NPAIR_), dim3(256), 0, stream>>>(weight, kerB);
    conv_mfma<<<dim3(16, 16, B_), dim3(512), 0, stream>>>(image, kerB, out, partials);
    stats_kernel<<<dim3(256), dim3(64), 0, stream>>>(partials, meanrs);
    norm2_kernel<<<dim3(16384), dim3(256), 0, stream>>>(out, meanrs);
}

// Round 12
// 120.446 us; speedup vs baseline: 1.4951x; 1.0430x over previous
//
#include <hip/hip_runtime.h>
#include <hip/hip_bf16.h>
#include <math.h>

// ---- static config ----
#define B_     8
#define CIN_   32
#define COUT_  32
#define H_     256
#define W_     256
#define K_     36
#define P_     3
#define KW_    7
#define TAPS_  49
#define NPAIR_ 25    // 21 within-row pairs (kx 0..5) + 4 kx=6 column pairs
#define EPS_   1e-5f
#define SLOPE_ 0.2f

// ws layout:
//   bytes [0 .. 102400)          kerB bf16 frags [4 oct][25 pair][64 lane][8]
//   bytes [102400 .. +512K)      partials float2 [256 bo][256 tile]
//   bytes [626688 .. +2K)        meanrs float2 [256 bo]
#define PART_OFF_F   25600   // float offset of partials
#define MEANRS_OFF_F 156672  // float offset of meanrs

// Img_s: fp32, 2 planes [ci-quad][20 py][21 px][4 ci], plane 6736 B
#define IMG_PLANE_B   6736
#define IMG_ROW_B     336

// Xup: ONE ci-octet per pass, parity-split, 38 rows (row 37 = zero pad
// read by the (ky6,pad) half of the last column pair):
//   even-x: 38 rows x 19 entries  base 0      11552 B
//   odd-x:  38 rows x 19 entries  base 11552  11552 B
// entry = 16 B (8 bf16 ci octet). row stride 304 B (=19*16 -> stage-2
// stores stay perfectly linear across y boundaries). total 23104 B.
#define XP_ROW   304
#define XO_BASE  11552

using short8_t  = __attribute__((ext_vector_type(8)))  short;
using f32x16_t  = __attribute__((ext_vector_type(16))) float;
using f32x4_t   = __attribute__((ext_vector_type(4)))  float;

__device__ inline ushort f32_to_bf16(float f) {
    unsigned int bits = __float_as_uint(f);
    unsigned int r = (bits + 0x7FFFu + ((bits >> 16) & 1u)) >> 16;
    return (ushort)r;
}

// pair pi, half tt -> linear tap (0..48), or -1 if zero pad
__host__ __device__ inline int pair_tap(int pi, int tt) {
    if (pi < 21) {
        const int ky = pi / 3, c = pi % 3;
        return ky * 7 + 2 * c + tt;
    }
    const int row = 2 * (pi - 21) + tt;
    return (row <= 6) ? (row * 7 + 6) : -1;
}

// ============================================================
// Kernel A: build B-fragments in the 25-pair packing. (r16, validated)
// ============================================================
__global__ __launch_bounds__(256)
void build_kernel(const float* __restrict__ weight, ushort* __restrict__ kerB) {
    __shared__ float psi_s[2][K_];            // psi for the pair's two taps
    const int f  = blockIdx.x;
    const int pi = f % NPAIR_;
    const int oc = f / NPAIR_;
    const int tid = threadIdx.x;

    if (tid < 2 * K_) {
        const int tt = tid / K_;              // which tap of the pair
        const int k  = tid - tt * K_;
        const int tap = pair_tap(pi, tt);
        float val = 0.f;
        if (tap >= 0) {
            const int ky = tap / 7;
            const int kx = tap % 7;
            const double dxy   = 2.0 / 512.0;
            const double rcut  = 0.015;       // RADIUS_CUTOFF / 2
            const int    nr    = 6, nphi = 7;
            const double dr    = rcut / nr;
            const double dphi  = 2.0 * M_PI / nphi;
            const double norm  = M_PI * (rcut * nr / (nr + 1)) * (rcut * nr / (nr + 1));
            const double q     = dxy * dxy;
            const double offy = (double)(ky - P_) * dxy;
            const double offx = (double)(kx - P_) * dxy;
            const double r    = sqrt(offx * offx + offy * offy);
            double phi = atan2(offy, offx);
            if (phi < 0.0) phi += 2.0 * M_PI;
            double ir, iphi;
            if (k == 0) { ir = 0.0; iphi = 0.0; }
            else        { ir = (double)((k - 1) / nphi + 1) * dr;
                          iphi = (double)((k - 1) % nphi) * dphi; }
            double rv = 1.0 - fabs(r - ir) / dr;
            rv = rv > 0.0 ? rv : 0.0;
            if (r > rcut) rv = 0.0;
            double pv = 1.0;
            if (k > 0) {
                double da = fabs(phi - iphi);
                double dm = da < (2.0 * M_PI - da) ? da : (2.0 * M_PI - da);
                pv = 1.0 - dm / dphi;
                pv = pv > 0.0 ? pv : 0.0;
            }
            val = (float)(rv * pv * q / norm);
        }
        psi_s[tt][k] = val;
    }
    __syncthreads();

    for (int e = tid; e < 512; e += 256) {
        const int lane = e >> 3;
        const int j    = e & 7;
        const int gs   = lane >> 5;
        const int n    = lane & 31;
        float s = 0.f;
        if (pair_tap(pi, gs) >= 0) {
            const int ci = oc * 8 + j;
            const float* w = weight + (size_t)(n * CIN_ + ci) * K_;
            #pragma unroll
            for (int k = 0; k < K_; ++k) s = fmaf(w[k], psi_s[gs][k], s);
        }
        kerB[((size_t)f * 64 + lane) * 8 + j] = f32_to_bf16(s);
    }
}

// ============================================================
// Kernel B: fused upsample + implicit-GEMM conv + stats partials.
// grid = (16,16,B), block = 512 (8 waves). Tile = 16x16 pixels x 32 cout.
// r20 = r16's validated body (conv 102.5 us; best total 116.8) with one
// safe delta: the post-stage-3 barrier is skipped on the last pass
// (epilogue touches only wp, which has its own barrier; race-checked
// in r19). Every other delta from r16 tried in r13/r15/r17/r18/r19
// was falsified (spill / L2-thrash / occupancy-cap) -- see journal.
// ============================================================
__global__ __launch_bounds__(512, 8)
void conv_mfma(const float* __restrict__ image,
               const ushort* __restrict__ kerB,
               float* __restrict__ out,
               float* __restrict__ partials) {
    __shared__ float  Img_s[3368];            // 13472 B (2 planes x 6736 B)
    __shared__ ushort Xup_s[11552];           // 23104 B (parity-split, 38 rows)
    __shared__ float  wp[8][32][2];           // per-wave stats partials

    const int tid  = threadIdx.x;
    const int lane = tid & 63;
    const int w    = tid >> 6;                // wave 0..7 = M-tile index
    const int j0 = blockIdx.x * 16;
    const int i0 = blockIdx.y * 16;
    const int b  = blockIdx.z;

    const int u0 = 2 * i0 - 3;
    const int v0 = 2 * j0 - 3;
    const int R0 = i0 - 2;                    // unclamped patch origin (rows)
    const int C0 = j0 - 2;                    // unclamped patch origin (cols)

    // A-fragment lane mapping (32x32x16): m = lane&31, k-half gs = lane>>5
    const int gs  = lane >> 5;                // which tap of the pair
    const int tio = (lane & 31) >> 4;
    const int tj  = lane & 15;
    const int yb0 = 4 * w + 2 * tio;

    f32x16_t acc;
    #pragma unroll
    for (int q = 0; q < 16; ++q) acc[q] = 0.f;

    char* img_bytes = (char*)Img_s;
    char* xup_bytes = (char*)Xup_s;

    // zero Xup even row 37 (pad) once; never overwritten afterwards
    if (tid < 19) {
        const short8_t z = {0,0,0,0,0,0,0,0};
        *(short8_t*)(xup_bytes + 37 * XP_ROW + tid * 16) = z;
    }

    const float* imgb = image + (size_t)(b * CIN_) * (H_ * W_);

    for (int oc = 0; oc < 4; ++oc) {
        // ---- stage 1: 20x20 patch, 2 ci-quad planes of this octet ----
        const float* img = imgb + (size_t)(oc * 8) * (H_ * W_);
        for (int e = tid; e < 800; e += 512) {
            const int p  = (e >= 400) ? 1 : 0;       // ci quad within octet
            const int yx = e - p * 400;
            const int py = yx / 20, px = yx - py * 20;
            const int row = R0 + py, col = C0 + px;
            f32x4_t g = {0.f, 0.f, 0.f, 0.f};
            if ((unsigned)row < 256u && (unsigned)col < 256u) {
                const float* q = img + (size_t)p * 4 * (H_ * W_) + row * W_ + col;
                g[0] = q[0];
                g[1] = q[H_ * W_];
                g[2] = q[2 * (H_ * W_)];
                g[3] = q[3 * (H_ * W_)];
            }
            *(f32x4_t*)(img_bytes + p * IMG_PLANE_B + (py * 21 + px) * 16) = g;
        }
        __syncthreads();

        // ---- stage 2: closed-form polyphase upsample, x-pair per item ----
        // ry = y>>1, wy = ((y&1)?510:255 - (R0+ry))/511 (align_corners 2x).
        for (int e = tid; e < 703; e += 512) {
            const int y   = e / 19;
            const int xp  = e - 19 * y;
            const int x   = 2 * xp;
            const int ry  = y >> 1;
            const float wy =
                (float)((((y & 1) ? 510 : 255)) - (R0 + ry)) * (1.0f / 511.0f);
            const int Ax = C0 + xp;
            const float wx0 = (float)(255 - Ax) * (1.0f / 511.0f);
            const float wx1 = (float)(510 - Ax) * (1.0f / 511.0f);
            const bool oky = ((unsigned)(u0 + y) < 512u);
            const bool ok0 = oky && ((unsigned)(v0 + x) < 512u);
            const bool ok1 = oky && ((unsigned)(v0 + x + 1) < 512u) && (xp < 18);

            const char* lo = img_bytes + (ry * 21 + xp) * 16;
            const char* hi = lo + IMG_PLANE_B;
            const f32x4_t a00 = *(const f32x4_t*)(lo);
            const f32x4_t a01 = *(const f32x4_t*)(lo + 16);
            const f32x4_t a10 = *(const f32x4_t*)(lo + IMG_ROW_B);
            const f32x4_t a11 = *(const f32x4_t*)(lo + IMG_ROW_B + 16);
            const f32x4_t b00 = *(const f32x4_t*)(hi);
            const f32x4_t b01 = *(const f32x4_t*)(hi + 16);
            const f32x4_t b10 = *(const f32x4_t*)(hi + IMG_ROW_B);
            const f32x4_t b11 = *(const f32x4_t*)(hi + IMG_ROW_B + 16);

            const f32x4_t cA0 = a00 + wy * (a10 - a00);
            const f32x4_t cA1 = a01 + wy * (a11 - a01);
            const f32x4_t cB0 = b00 + wy * (b10 - b00);
            const f32x4_t cB1 = b01 + wy * (b11 - b01);

            // even output -> even buffer (linear store)
            {
                const f32x4_t va = cA0 + wx0 * (cA1 - cA0);
                const f32x4_t vb = cB0 + wx0 * (cB1 - cB0);
                __hip_bfloat162 h0 = __float22bfloat162_rn(make_float2(va[0], va[1]));
                __hip_bfloat162 h1 = __float22bfloat162_rn(make_float2(va[2], va[3]));
                __hip_bfloat162 h2 = __float22bfloat162_rn(make_float2(vb[0], vb[1]));
                __hip_bfloat162 h3 = __float22bfloat162_rn(make_float2(vb[2], vb[3]));
                union { short8_t s8; uint4 u4; } pk;
                pk.u4.x = ok0 ? *(unsigned int*)&h0 : 0u;
                pk.u4.y = ok0 ? *(unsigned int*)&h1 : 0u;
                pk.u4.z = ok0 ? *(unsigned int*)&h2 : 0u;
                pk.u4.w = ok0 ? *(unsigned int*)&h3 : 0u;
                *(short8_t*)(xup_bytes + y * XP_ROW + xp * 16) = pk.s8;
            }
            // odd output -> odd buffer; xp==18 writes the zero pad entry
            {
                const f32x4_t va = cA0 + wx1 * (cA1 - cA0);
                const f32x4_t vb = cB0 + wx1 * (cB1 - cB0);
                __hip_bfloat162 h0 = __float22bfloat162_rn(make_float2(va[0], va[1]));
                __hip_bfloat162 h1 = __float22bfloat162_rn(make_float2(va[2], va[3]));
                __hip_bfloat162 h2 = __float22bfloat162_rn(make_float2(vb[0], vb[1]));
                __hip_bfloat162 h3 = __float22bfloat162_rn(make_float2(vb[2], vb[3]));
                union { short8_t s8; uint4 u4; } pk;
                pk.u4.x = ok1 ? *(unsigned int*)&h0 : 0u;
                pk.u4.y = ok1 ? *(unsigned int*)&h1 : 0u;
                pk.u4.z = ok1 ? *(unsigned int*)&h2 : 0u;
                pk.u4.w = ok1 ? *(unsigned int*)&h3 : 0u;
                *(short8_t*)(xup_bytes + XO_BASE + y * XP_ROW + xp * 16) = pk.s8;
            }
        }
        __syncthreads();

        // ---- stage 3: 21 within-row pairs + 4 column pairs = 25 MFMAs ----
        const ushort* kbp = kerB + ((size_t)(oc * NPAIR_) * 64 + lane) * 8;
        // group A base: parity buffer = gs, row yb0+ky, entry tj+c
        const int baseA = (gs ? XO_BASE : 0) + yb0 * XP_ROW + tj * 16;
        // group B base: even buffer, row yb0+2q+gs, entry tj+3
        const int baseB = (yb0 + gs) * XP_ROW + (tj + 3) * 16;

        #pragma unroll
        for (int ky = 0; ky < KW_; ++ky) {
            short8_t bf0 = *(const short8_t*)(kbp + (size_t)((ky * 3 + 0) * 512));
            short8_t bf1 = *(const short8_t*)(kbp + (size_t)((ky * 3 + 1) * 512));
            short8_t bf2 = *(const short8_t*)(kbp + (size_t)((ky * 3 + 2) * 512));
            const int rbase = baseA + ky * XP_ROW;
            const short8_t a0 = *(const short8_t*)(xup_bytes + rbase);
            acc = __builtin_amdgcn_mfma_f32_32x32x16_bf16(a0, bf0, acc, 0, 0, 0);
            const short8_t a1 = *(const short8_t*)(xup_bytes + rbase + 16);
            acc = __builtin_amdgcn_mfma_f32_32x32x16_bf16(a1, bf1, acc, 0, 0, 0);
            const short8_t a2 = *(const short8_t*)(xup_bytes + rbase + 32);
            acc = __builtin_amdgcn_mfma_f32_32x32x16_bf16(a2, bf2, acc, 0, 0, 0);
        }
        #pragma unroll
        for (int q = 0; q < 4; ++q) {
            const short8_t bfq =
                *(const short8_t*)(kbp + (size_t)((21 + q) * 512));
            const short8_t aq =
                *(const short8_t*)(xup_bytes + baseB + q * (2 * XP_ROW));
            acc = __builtin_amdgcn_mfma_f32_32x32x16_bf16(aq, bfq, acc, 0, 0, 0);
        }
        if (oc != 3) __syncthreads();   // last pass: epilogue touches only wp
    }

    // ---- epilogue: C-writes (layout col n=lane&31, row m=(q&3)+8*(q>>2)+4*gs)
    const int n = lane & 31;
    float* op = out + (size_t)(b * COUT_ + n) * (H_ * W_);
    const int ibase = i0 + 2 * w;
    #pragma unroll
    for (int grp = 0; grp < 4; ++grp) {
        const int ti  = ibase + (grp >> 1);
        const int tjj = j0 + ((grp & 1) ? 8 : 0) + 4 * gs;
        f32x4_t s;
        s[0] = acc[grp * 4 + 0]; s[1] = acc[grp * 4 + 1];
        s[2] = acc[grp * 4 + 2]; s[3] = acc[grp * 4 + 3];
        *(f32x4_t*)(op + (size_t)ti * W_ + tjj) = s;
    }

    // ---- epilogue: InstanceNorm partial sums from registers ----
    float s1 = 0.f, s2 = 0.f;
    #pragma unroll
    for (int q = 0; q < 16; ++q) { s1 += acc[q]; s2 = fmaf(acc[q], acc[q], s2); }
    s1 += __shfl_xor(s1, 32);
    s2 += __shfl_xor(s2, 32);
    if (lane < 32) { wp[w][lane][0] = s1; wp[w][lane][1] = s2; }
    __syncthreads();
    if (tid < 32) {
        float t1 = 0.f, t2 = 0.f;
        #pragma unroll
        for (int wv = 0; wv < 8; ++wv) { t1 += wp[wv][tid][0]; t2 += wp[wv][tid][1]; }
        const int tile = blockIdx.y * 16 + blockIdx.x;
        float2* pp = (float2*)partials;
        pp[((b * 32 + tid) << 8) | tile] = make_float2(t1, t2);
    }
}

// ============================================================
// Kernel C1: per-channel stats finalize. grid = 256 (one wave each).
// Fixed-order shfl tree -> deterministic.
// ============================================================
__global__ __launch_bounds__(64)
void stats_kernel(const float* __restrict__ partials, float* __restrict__ meanrs) {
    const int bo = blockIdx.x;                 // channel (b*32+o)
    const int l  = threadIdx.x;                // 0..63
    const float2* pp = (const float2*)partials + ((size_t)bo << 8);
    float s1 = 0.f, s2 = 0.f;
    #pragma unroll
    for (int k = 0; k < 4; ++k) {
        const float2 p = pp[l + 64 * k];
        s1 += p.x; s2 += p.y;
    }
    #pragma unroll
    for (int off = 32; off > 0; off >>= 1) {
        s1 += __shfl_down(s1, off);
        s2 += __shfl_down(s2, off);
    }
    if (l == 0) {
        const float inv = 1.0f / 65536.0f;
        const float m   = s1 * inv;
        const float var = s2 * inv - m * m;
        ((float2*)meanrs)[bo] = make_float2(m, 1.0f / sqrtf(var + EPS_));
    }
}

// ============================================================
// Kernel C2: pure-stream normalize + LeakyReLU (no LDS, no barriers).
// grid = 16384, block = 256.
// ============================================================
__global__ __launch_bounds__(256)
void norm2_kernel(float* __restrict__ y, const float* __restrict__ meanrs) {
    const int blk = blockIdx.x;
    const int bo  = blk >> 6;                  // 64 blocks per channel
    const float2 mr = ((const float2*)meanrs)[bo];
    const float m  = mr.x;
    const float rs = mr.y;

    const int e = blk * 256 + threadIdx.x;     // float4 index
    float4 v = ((const float4*)y)[e];
    v.x = (v.x - m) * rs; v.x = v.x >= 0.f ? v.x : SLOPE_ * v.x;
    v.y = (v.y - m) * rs; v.y = v.y >= 0.f ? v.y : SLOPE_ * v.y;
    v.z = (v.z - m) * rs; v.z = v.z >= 0.f ? v.z : SLOPE_ * v.z;
    v.w = (v.w - m) * rs; v.w = v.w >= 0.f ? v.w : SLOPE_ * v.w;
    ((float4*)y)[e] = v;
}

// ============================================================
extern "C" void kernel_launch(void* const* d_in, const int* in_sizes, int n_in,
                              void* d_out, int out_size, void* d_ws, size_t ws_size,
                              hipStream_t stream) {
    const float* image  = (const float*)d_in[0];
    const float* weight = (const float*)d_in[1];
    float*  out      = (float*)d_out;
    ushort* kerB     = (ushort*)d_ws;
    float*  partials = (float*)d_ws + PART_OFF_F;
    float*  meanrs   = (float*)d_ws + MEANRS_OFF_F;

    build_kernel<<<dim3(4 * NPAIR_), dim3(256), 0, stream>>>(weight, kerB);
    conv_mfma<<<dim3(16, 16, B_), dim3(512), 0, stream>>>(image, kerB, out, partials);
    stats_kernel<<<dim3(256), dim3(64), 0, stream>>>(partials, meanrs);
    norm2_kernel<<<dim3(16384), dim3(256), 0, stream>>>(out, meanrs);
}

// Round 13
// 119.966 us; speedup vs baseline: 1.5011x; 1.0040x over previous
//
#include <hip/hip_runtime.h>
#include <hip/hip_bf16.h>
#include <math.h>

// ---- static config ----
#define B_     8
#define CIN_   32
#define COUT_  32
#define H_     256
#define W_     256
#define K_     36
#define P_     3
#define KW_    7
#define TAPS_  49
#define NPAIR_ 25    // 21 within-row pairs (kx 0..5) + 4 kx=6 column pairs
#define EPS_   1e-5f
#define SLOPE_ 0.2f

// ws layout:
//   bytes [0 .. 102400)          kerB bf16 frags [4 oct][25 pair][64 lane][8]
//   bytes [102400 .. +512K)      partials float2 [256 bo][256 tile]
//   bytes [626688 .. +2K)        meanrs float2 [256 bo]
#define PART_OFF_F   25600   // float offset of partials
#define MEANRS_OFF_F 156672  // float offset of meanrs

// Img_s: fp32, 2 planes [ci-quad][20 py][21 px][4 ci], plane 6736 B
#define IMG_PLANE_B   6736
#define IMG_ROW_B     336

// Xup: ONE ci-octet per pass, parity-split, 38 rows (row 37 = zero pad
// read by the (ky6,pad) half of the last column pair):
//   even-x: 38 rows x 19 entries  base 0      11552 B
//   odd-x:  38 rows x 19 entries  base 11552  11552 B
// entry = 16 B (8 bf16 ci octet). row stride 304 B (=19*16 -> stage-2
// stores stay perfectly linear across y boundaries). total 23104 B.
#define XP_ROW   304
#define XO_BASE  11552

using short8_t  = __attribute__((ext_vector_type(8)))  short;
using f32x16_t  = __attribute__((ext_vector_type(16))) float;
using f32x4_t   = __attribute__((ext_vector_type(4)))  float;

__device__ inline ushort f32_to_bf16(float f) {
    unsigned int bits = __float_as_uint(f);
    unsigned int r = (bits + 0x7FFFu + ((bits >> 16) & 1u)) >> 16;
    return (ushort)r;
}

// pair pi, half tt -> linear tap (0..48), or -1 if zero pad
__host__ __device__ inline int pair_tap(int pi, int tt) {
    if (pi < 21) {
        const int ky = pi / 3, c = pi % 3;
        return ky * 7 + 2 * c + tt;
    }
    const int row = 2 * (pi - 21) + tt;
    return (row <= 6) ? (row * 7 + 6) : -1;
}

// ============================================================
// Kernel A: build B-fragments in the 25-pair packing. (r16, validated)
// ============================================================
__global__ __launch_bounds__(256)
void build_kernel(const float* __restrict__ weight, ushort* __restrict__ kerB) {
    __shared__ float psi_s[2][K_];            // psi for the pair's two taps
    const int f  = blockIdx.x;
    const int pi = f % NPAIR_;
    const int oc = f / NPAIR_;
    const int tid = threadIdx.x;

    if (tid < 2 * K_) {
        const int tt = tid / K_;              // which tap of the pair
        const int k  = tid - tt * K_;
        const int tap = pair_tap(pi, tt);
        float val = 0.f;
        if (tap >= 0) {
            const int ky = tap / 7;
            const int kx = tap % 7;
            const double dxy   = 2.0 / 512.0;
            const double rcut  = 0.015;       // RADIUS_CUTOFF / 2
            const int    nr    = 6, nphi = 7;
            const double dr    = rcut / nr;
            const double dphi  = 2.0 * M_PI / nphi;
            const double norm  = M_PI * (rcut * nr / (nr + 1)) * (rcut * nr / (nr + 1));
            const double q     = dxy * dxy;
            const double offy = (double)(ky - P_) * dxy;
            const double offx = (double)(kx - P_) * dxy;
            const double r    = sqrt(offx * offx + offy * offy);
            double phi = atan2(offy, offx);
            if (phi < 0.0) phi += 2.0 * M_PI;
            double ir, iphi;
            if (k == 0) { ir = 0.0; iphi = 0.0; }
            else        { ir = (double)((k - 1) / nphi + 1) * dr;
                          iphi = (double)((k - 1) % nphi) * dphi; }
            double rv = 1.0 - fabs(r - ir) / dr;
            rv = rv > 0.0 ? rv : 0.0;
            if (r > rcut) rv = 0.0;
            double pv = 1.0;
            if (k > 0) {
                double da = fabs(phi - iphi);
                double dm = da < (2.0 * M_PI - da) ? da : (2.0 * M_PI - da);
                pv = 1.0 - dm / dphi;
                pv = pv > 0.0 ? pv : 0.0;
            }
            val = (float)(rv * pv * q / norm);
        }
        psi_s[tt][k] = val;
    }
    __syncthreads();

    for (int e = tid; e < 512; e += 256) {
        const int lane = e >> 3;
        const int j    = e & 7;
        const int gs   = lane >> 5;
        const int n    = lane & 31;
        float s = 0.f;
        if (pair_tap(pi, gs) >= 0) {
            const int ci = oc * 8 + j;
            const float* w = weight + (size_t)(n * CIN_ + ci) * K_;
            #pragma unroll
            for (int k = 0; k < K_; ++k) s = fmaf(w[k], psi_s[gs][k], s);
        }
        kerB[((size_t)f * 64 + lane) * 8 + j] = f32_to_bf16(s);
    }
}

// ============================================================
// Kernel B: fused upsample + implicit-GEMM conv + stats partials.
// grid = (16,16,B), block = 512 (8 waves). Tile = 16x16 pixels x 32 cout.
// r21 = r20 (validated r16 body + last-pass barrier skip) + T5:
//   s_setprio(1) around the 25-MFMA stage-3 cluster. Mechanism: 4
//   independent blocks/CU sit at different phases; priority lets the
//   MFMA-issuing waves win issue arbitration over other blocks' staging
//   waves. Zero codegen-visible data change (no spill risk).
// ============================================================
__global__ __launch_bounds__(512, 8)
void conv_mfma(const float* __restrict__ image,
               const ushort* __restrict__ kerB,
               float* __restrict__ out,
               float* __restrict__ partials) {
    __shared__ float  Img_s[3368];            // 13472 B (2 planes x 6736 B)
    __shared__ ushort Xup_s[11552];           // 23104 B (parity-split, 38 rows)
    __shared__ float  wp[8][32][2];           // per-wave stats partials

    const int tid  = threadIdx.x;
    const int lane = tid & 63;
    const int w    = tid >> 6;                // wave 0..7 = M-tile index
    const int j0 = blockIdx.x * 16;
    const int i0 = blockIdx.y * 16;
    const int b  = blockIdx.z;

    const int u0 = 2 * i0 - 3;
    const int v0 = 2 * j0 - 3;
    const int R0 = i0 - 2;                    // unclamped patch origin (rows)
    const int C0 = j0 - 2;                    // unclamped patch origin (cols)

    // A-fragment lane mapping (32x32x16): m = lane&31, k-half gs = lane>>5
    const int gs  = lane >> 5;                // which tap of the pair
    const int tio = (lane & 31) >> 4;
    const int tj  = lane & 15;
    const int yb0 = 4 * w + 2 * tio;

    f32x16_t acc;
    #pragma unroll
    for (int q = 0; q < 16; ++q) acc[q] = 0.f;

    char* img_bytes = (char*)Img_s;
    char* xup_bytes = (char*)Xup_s;

    // zero Xup even row 37 (pad) once; never overwritten afterwards
    if (tid < 19) {
        const short8_t z = {0,0,0,0,0,0,0,0};
        *(short8_t*)(xup_bytes + 37 * XP_ROW + tid * 16) = z;
    }

    const float* imgb = image + (size_t)(b * CIN_) * (H_ * W_);

    for (int oc = 0; oc < 4; ++oc) {
        // ---- stage 1: 20x20 patch, 2 ci-quad planes of this octet ----
        const float* img = imgb + (size_t)(oc * 8) * (H_ * W_);
        for (int e = tid; e < 800; e += 512) {
            const int p  = (e >= 400) ? 1 : 0;       // ci quad within octet
            const int yx = e - p * 400;
            const int py = yx / 20, px = yx - py * 20;
            const int row = R0 + py, col = C0 + px;
            f32x4_t g = {0.f, 0.f, 0.f, 0.f};
            if ((unsigned)row < 256u && (unsigned)col < 256u) {
                const float* q = img + (size_t)p * 4 * (H_ * W_) + row * W_ + col;
                g[0] = q[0];
                g[1] = q[H_ * W_];
                g[2] = q[2 * (H_ * W_)];
                g[3] = q[3 * (H_ * W_)];
            }
            *(f32x4_t*)(img_bytes + p * IMG_PLANE_B + (py * 21 + px) * 16) = g;
        }
        __syncthreads();

        // ---- stage 2: closed-form polyphase upsample, x-pair per item ----
        // ry = y>>1, wy = ((y&1)?510:255 - (R0+ry))/511 (align_corners 2x).
        for (int e = tid; e < 703; e += 512) {
            const int y   = e / 19;
            const int xp  = e - 19 * y;
            const int x   = 2 * xp;
            const int ry  = y >> 1;
            const float wy =
                (float)((((y & 1) ? 510 : 255)) - (R0 + ry)) * (1.0f / 511.0f);
            const int Ax = C0 + xp;
            const float wx0 = (float)(255 - Ax) * (1.0f / 511.0f);
            const float wx1 = (float)(510 - Ax) * (1.0f / 511.0f);
            const bool oky = ((unsigned)(u0 + y) < 512u);
            const bool ok0 = oky && ((unsigned)(v0 + x) < 512u);
            const bool ok1 = oky && ((unsigned)(v0 + x + 1) < 512u) && (xp < 18);

            const char* lo = img_bytes + (ry * 21 + xp) * 16;
            const char* hi = lo + IMG_PLANE_B;
            const f32x4_t a00 = *(const f32x4_t*)(lo);
            const f32x4_t a01 = *(const f32x4_t*)(lo + 16);
            const f32x4_t a10 = *(const f32x4_t*)(lo + IMG_ROW_B);
            const f32x4_t a11 = *(const f32x4_t*)(lo + IMG_ROW_B + 16);
            const f32x4_t b00 = *(const f32x4_t*)(hi);
            const f32x4_t b01 = *(const f32x4_t*)(hi + 16);
            const f32x4_t b10 = *(const f32x4_t*)(hi + IMG_ROW_B);
            const f32x4_t b11 = *(const f32x4_t*)(hi + IMG_ROW_B + 16);

            const f32x4_t cA0 = a00 + wy * (a10 - a00);
            const f32x4_t cA1 = a01 + wy * (a11 - a01);
            const f32x4_t cB0 = b00 + wy * (b10 - b00);
            const f32x4_t cB1 = b01 + wy * (b11 - b01);

            // even output -> even buffer (linear store)
            {
                const f32x4_t va = cA0 + wx0 * (cA1 - cA0);
                const f32x4_t vb = cB0 + wx0 * (cB1 - cB0);
                __hip_bfloat162 h0 = __float22bfloat162_rn(make_float2(va[0], va[1]));
                __hip_bfloat162 h1 = __float22bfloat162_rn(make_float2(va[2], va[3]));
                __hip_bfloat162 h2 = __float22bfloat162_rn(make_float2(vb[0], vb[1]));
                __hip_bfloat162 h3 = __float22bfloat162_rn(make_float2(vb[2], vb[3]));
                union { short8_t s8; uint4 u4; } pk;
                pk.u4.x = ok0 ? *(unsigned int*)&h0 : 0u;
                pk.u4.y = ok0 ? *(unsigned int*)&h1 : 0u;
                pk.u4.z = ok0 ? *(unsigned int*)&h2 : 0u;
                pk.u4.w = ok0 ? *(unsigned int*)&h3 : 0u;
                *(short8_t*)(xup_bytes + y * XP_ROW + xp * 16) = pk.s8;
            }
            // odd output -> odd buffer; xp==18 writes the zero pad entry
            {
                const f32x4_t va = cA0 + wx1 * (cA1 - cA0);
                const f32x4_t vb = cB0 + wx1 * (cB1 - cB0);
                __hip_bfloat162 h0 = __float22bfloat162_rn(make_float2(va[0], va[1]));
                __hip_bfloat162 h1 = __float22bfloat162_rn(make_float2(va[2], va[3]));
                __hip_bfloat162 h2 = __float22bfloat162_rn(make_float2(vb[0], vb[1]));
                __hip_bfloat162 h3 = __float22bfloat162_rn(make_float2(vb[2], vb[3]));
                union { short8_t s8; uint4 u4; } pk;
                pk.u4.x = ok1 ? *(unsigned int*)&h0 : 0u;
                pk.u4.y = ok1 ? *(unsigned int*)&h1 : 0u;
                pk.u4.z = ok1 ? *(unsigned int*)&h2 : 0u;
                pk.u4.w = ok1 ? *(unsigned int*)&h3 : 0u;
                *(short8_t*)(xup_bytes + XO_BASE + y * XP_ROW + xp * 16) = pk.s8;
            }
        }
        __syncthreads();

        // ---- stage 3: 21 within-row pairs + 4 column pairs = 25 MFMAs ----
        const ushort* kbp = kerB + ((size_t)(oc * NPAIR_) * 64 + lane) * 8;
        // group A base: parity buffer = gs, row yb0+ky, entry tj+c
        const int baseA = (gs ? XO_BASE : 0) + yb0 * XP_ROW + tj * 16;
        // group B base: even buffer, row yb0+2q+gs, entry tj+3
        const int baseB = (yb0 + gs) * XP_ROW + (tj + 3) * 16;

        __builtin_amdgcn_s_setprio(1);     // T5: favor MFMA-issuing waves
        #pragma unroll
        for (int ky = 0; ky < KW_; ++ky) {
            short8_t bf0 = *(const short8_t*)(kbp + (size_t)((ky * 3 + 0) * 512));
            short8_t bf1 = *(const short8_t*)(kbp + (size_t)((ky * 3 + 1) * 512));
            short8_t bf2 = *(const short8_t*)(kbp + (size_t)((ky * 3 + 2) * 512));
            const int rbase = baseA + ky * XP_ROW;
            const short8_t a0 = *(const short8_t*)(xup_bytes + rbase);
            acc = __builtin_amdgcn_mfma_f32_32x32x16_bf16(a0, bf0, acc, 0, 0, 0);
            const short8_t a1 = *(const short8_t*)(xup_bytes + rbase + 16);
            acc = __builtin_amdgcn_mfma_f32_32x32x16_bf16(a1, bf1, acc, 0, 0, 0);
            const short8_t a2 = *(const short8_t*)(xup_bytes + rbase + 32);
            acc = __builtin_amdgcn_mfma_f32_32x32x16_bf16(a2, bf2, acc, 0, 0, 0);
        }
        #pragma unroll
        for (int q = 0; q < 4; ++q) {
            const short8_t bfq =
                *(const short8_t*)(kbp + (size_t)((21 + q) * 512));
            const short8_t aq =
                *(const short8_t*)(xup_bytes + baseB + q * (2 * XP_ROW));
            acc = __builtin_amdgcn_mfma_f32_32x32x16_bf16(aq, bfq, acc, 0, 0, 0);
        }
        __builtin_amdgcn_s_setprio(0);
        if (oc != 3) __syncthreads();   // last pass: epilogue touches only wp
    }

    // ---- epilogue: C-writes (layout col n=lane&31, row m=(q&3)+8*(q>>2)+4*gs)
    const int n = lane & 31;
    float* op = out + (size_t)(b * COUT_ + n) * (H_ * W_);
    const int ibase = i0 + 2 * w;
    #pragma unroll
    for (int grp = 0; grp < 4; ++grp) {
        const int ti  = ibase + (grp >> 1);
        const int tjj = j0 + ((grp & 1) ? 8 : 0) + 4 * gs;
        f32x4_t s;
        s[0] = acc[grp * 4 + 0]; s[1] = acc[grp * 4 + 1];
        s[2] = acc[grp * 4 + 2]; s[3] = acc[grp * 4 + 3];
        *(f32x4_t*)(op + (size_t)ti * W_ + tjj) = s;
    }

    // ---- epilogue: InstanceNorm partial sums from registers ----
    float s1 = 0.f, s2 = 0.f;
    #pragma unroll
    for (int q = 0; q < 16; ++q) { s1 += acc[q]; s2 = fmaf(acc[q], acc[q], s2); }
    s1 += __shfl_xor(s1, 32);
    s2 += __shfl_xor(s2, 32);
    if (lane < 32) { wp[w][lane][0] = s1; wp[w][lane][1] = s2; }
    __syncthreads();
    if (tid < 32) {
        float t1 = 0.f, t2 = 0.f;
        #pragma unroll
        for (int wv = 0; wv < 8; ++wv) { t1 += wp[wv][tid][0]; t2 += wp[wv][tid][1]; }
        const int tile = blockIdx.y * 16 + blockIdx.x;
        float2* pp = (float2*)partials;
        pp[((b * 32 + tid) << 8) | tile] = make_float2(t1, t2);
    }
}

// ============================================================
// Kernel C1: per-channel stats finalize. grid = 256 (one wave each).
// Fixed-order shfl tree -> deterministic.
// ============================================================
__global__ __launch_bounds__(64)
void stats_kernel(const float* __restrict__ partials, float* __restrict__ meanrs) {
    const int bo = blockIdx.x;                 // channel (b*32+o)
    const int l  = threadIdx.x;                // 0..63
    const float2* pp = (const float2*)partials + ((size_t)bo << 8);
    float s1 = 0.f, s2 = 0.f;
    #pragma unroll
    for (int k = 0; k < 4; ++k) {
        const float2 p = pp[l + 64 * k];
        s1 += p.x; s2 += p.y;
    }
    #pragma unroll
    for (int off = 32; off > 0; off >>= 1) {
        s1 += __shfl_down(s1, off);
        s2 += __shfl_down(s2, off);
    }
    if (l == 0) {
        const float inv = 1.0f / 65536.0f;
        const float m   = s1 * inv;
        const float var = s2 * inv - m * m;
        ((float2*)meanrs)[bo] = make_float2(m, 1.0f / sqrtf(var + EPS_));
    }
}

// ============================================================
// Kernel C2: pure-stream normalize + LeakyReLU (no LDS, no barriers).
// grid = 16384, block = 256.
// ============================================================
__global__ __launch_bounds__(256)
void norm2_kernel(float* __restrict__ y, const float* __restrict__ meanrs) {
    const int blk = blockIdx.x;
    const int bo  = blk >> 6;                  // 64 blocks per channel
    const float2 mr = ((const float2*)meanrs)[bo];
    const float m  = mr.x;
    const float rs = mr.y;

    const int e = blk * 256 + threadIdx.x;     // float4 index
    float4 v = ((const float4*)y)[e];
    v.x = (v.x - m) * rs; v.x = v.x >= 0.f ? v.x : SLOPE_ * v.x;
    v.y = (v.y - m) * rs; v.y = v.y >= 0.f ? v.y : SLOPE_ * v.y;
    v.z = (v.z - m) * rs; v.z = v.z >= 0.f ? v.z : SLOPE_ * v.z;
    v.w = (v.w - m) * rs; v.w = v.w >= 0.f ? v.w : SLOPE_ * v.w;
    ((float4*)y)[e] = v;
}

// ============================================================
extern "C" void kernel_launch(void* const* d_in, const int* in_sizes, int n_in,
                              void* d_out, int out_size, void* d_ws, size_t ws_size,
                              hipStream_t stream) {
    const float* image  = (const float*)d_in[0];
    const float* weight = (const float*)d_in[1];
    float*  out      = (float*)d_out;
    ushort* kerB     = (ushort*)d_ws;
    float*  partials = (float*)d_ws + PART_OFF_F;
    float*  meanrs   = (float*)d_ws + MEANRS_OFF_F;

    build_kernel<<<dim3(4 * NPAIR_), dim3(256), 0, stream>>>(weight, kerB);
    conv_mfma<<<dim3(16, 16, B_), dim3(512), 0, stream>>>(image, kerB, out, partials);
    stats_kernel<<<dim3(256), dim3(64), 0, stream>>>(partials, meanrs);
    norm2_kernel<<<dim3(16384), dim3(256), 0, stream>>>(out, meanrs);
}